// Round 9
// baseline (200.442 us; speedup 1.0000x reference)
//
#include <hip/hip_runtime.h>
#include <math.h>

#define N_PROP 300
#define N_CLS  80
#define N_GT   24
#define N_B    4
#define CF     128
#define HF     64
#define HM     224
#define TT     28
#define ALPHA  0.25f
#define EPSV   1e-8f
#define CAND_K 10
#define CENTER_R 44.8f
#define S_IMG 896.0f

// ---------- device helpers ----------

__device__ __forceinline__ float iou_unnorm(const float* a, const float* g) {
    float lx = fmaxf(a[0], g[0]), ly = fmaxf(a[1], g[1]);
    float rx = fminf(a[2], g[2]), ry = fminf(a[3], g[3]);
    float w = fmaxf(rx - lx, 0.f), h = fmaxf(ry - ly, 0.f);
    float inter = w * h;
    float aa = fmaxf(a[2] - a[0], 0.f) * fmaxf(a[3] - a[1], 0.f);
    float ag = fmaxf(g[2] - g[0], 0.f) * fmaxf(g[3] - g[1], 0.f);
    float uni = aa + ag - inter;
    return inter / (uni + EPSV);
}

__device__ __forceinline__ float giou_pair(const float* a, const float* g) {
    float lx = fmaxf(a[0], g[0]), ly = fmaxf(a[1], g[1]);
    float rx = fminf(a[2], g[2]), ry = fminf(a[3], g[3]);
    float w = fmaxf(rx - lx, 0.f), h = fmaxf(ry - ly, 0.f);
    float inter = w * h;
    float aa = fmaxf(a[2] - a[0], 0.f) * fmaxf(a[3] - a[1], 0.f);
    float ag = fmaxf(g[2] - g[0], 0.f) * fmaxf(g[3] - g[1], 0.f);
    float uni = aa + ag - inter;
    float iou = inter / (uni + EPSV);
    float elx = fminf(a[0], g[0]), ely = fminf(a[1], g[1]);
    float erx = fmaxf(a[2], g[2]), ery = fmaxf(a[3], g[3]);
    float ew = fmaxf(erx - elx, 0.f), eh = fmaxf(ery - ely, 0.f);
    float enc = ew * eh;
    return iou - (enc - uni) / (enc + EPSV);
}

__device__ __forceinline__ float bilin(const float* img, int H, int W, float X, float Y) {
    float x0f = fminf(fmaxf(floorf(X), 0.f), (float)(W - 1));
    float y0f = fminf(fmaxf(floorf(Y), 0.f), (float)(H - 1));
    float wx = fminf(fmaxf(X - x0f, 0.f), 1.f);
    float wy = fminf(fmaxf(Y - y0f, 0.f), 1.f);
    int x0 = (int)x0f, y0 = (int)y0f;
    int x1 = min(x0 + 1, W - 1), y1 = min(y0 + 1, H - 1);
    float v00 = img[y0 * W + x0], v01 = img[y0 * W + x1];
    float v10 = img[y1 * W + x0], v11 = img[y1 * W + x1];
    return v00 * (1.f - wx) * (1.f - wy) + v01 * wx * (1.f - wy)
         + v10 * (1.f - wx) * wy + v11 * wx * wy;
}

__device__ __forceinline__ float focal_term(float x, float label) {
    float p = 1.f / (1.f + expf(-x));
    float ce = fmaxf(x, 0.f) + log1pf(expf(-fabsf(x))) - x * label;
    float pt = p * label + (1.f - p) * (1.f - label);
    float at = ALPHA * label + (1.f - ALPHA) * (1.f - label);
    return at * (1.f - pt) * (1.f - pt) * ce;
}

// ---------- K1: proj (blocks 0..255) + gcrop (blocks 256..351) + cnt zero ----------
__global__ __launch_bounds__(256) void prep_kernel(
    const float* __restrict__ feat, const float* __restrict__ wm,
    const int* __restrict__ gtcls, const float* __restrict__ gtbox,
    const float* __restrict__ gmask, float* __restrict__ proj,
    float* __restrict__ gcrop, float* __restrict__ gsum, int* __restrict__ cnt)
{
    int blk = blockIdx.x;
    int tid = threadIdx.x;
    if (blk == 0 && tid == 0) *cnt = 0;

    __shared__ __align__(16) float s_w[CF][N_GT];       // 12 KB (proj role)
    __shared__ float s_acc[4][64][N_GT + 1];            // pad -> conflict-free
    __shared__ float s_rs[4];                            // gcrop role reduce

    if (blk < 256) {
        // ---------------- proj role ----------------
        int b = blk >> 6;
        int chunk = blk & 63;
        for (int k = tid; k < N_GT * CF; k += 256) {
            int j = k >> 7, f = k & 127;
            s_w[f][j] = wm[gtcls[b * N_GT + j] * CF + f];
        }
        __syncthreads();

        int px = tid & 63;
        int fq = tid >> 6;
        int pix = chunk * 64 + px;
        const float* fb = feat + ((size_t)b * CF + fq * 32) * (HF * HF) + pix;
        float accv[N_GT];
        #pragma unroll
        for (int j = 0; j < N_GT; j++) accv[j] = 0.f;
        #pragma unroll 8
        for (int f = 0; f < 32; f++) {
            float v = fb[(size_t)f * HF * HF];
            const float4* wrow = (const float4*)&s_w[fq * 32 + f][0];
            #pragma unroll
            for (int q = 0; q < 6; q++) {
                float4 wv = wrow[q];
                accv[q * 4 + 0] = fmaf(wv.x, v, accv[q * 4 + 0]);
                accv[q * 4 + 1] = fmaf(wv.y, v, accv[q * 4 + 1]);
                accv[q * 4 + 2] = fmaf(wv.z, v, accv[q * 4 + 2]);
                accv[q * 4 + 3] = fmaf(wv.w, v, accv[q * 4 + 3]);
            }
        }
        #pragma unroll
        for (int j = 0; j < N_GT; j++) s_acc[fq][px][j] = accv[j];
        __syncthreads();
        for (int o = tid; o < 64 * N_GT; o += 256) {
            int j = o >> 6, p2 = o & 63;
            float s = s_acc[0][p2][j] + s_acc[1][p2][j] + s_acc[2][p2][j] + s_acc[3][p2][j];
            proj[(size_t)(b * N_GT + j) * (HF * HF) + chunk * 64 + p2] = s;
        }
    } else {
        // ---------------- gcrop role: one block per (b, j) ----------------
        int bj = blk - 256;
        int b = bj / N_GT;
        int j = bj - b * N_GT;
        const float* gimg = gmask + (size_t)(b * N_GT + j) * HM * HM;
        float4 g4 = ((const float4*)gtbox)[b * N_GT + j];
        const float ms = 224.0f / 896.0f;
        float gx1 = g4.x * ms, gy1 = g4.y * ms, gx2 = g4.z * ms, gy2 = g4.w * ms;
        float sg = 0.f;
        #pragma unroll 4
        for (int t = tid; t < TT * TT; t += 256) {
            int ty = t / TT, tx = t - ty * TT;
            float qx = ((float)tx + 0.5f) / (float)TT;
            float qy = ((float)ty + 0.5f) / (float)TT;
            float Xg = gx1 + (gx2 - gx1) * qx - 0.5f;
            float Yg = gy1 + (gy2 - gy1) * qy - 0.5f;
            float gc = bilin(gimg, HM, HM, Xg, Yg);
            gcrop[(size_t)bj * (TT * TT) + t] = gc;
            sg += gc;
        }
        #pragma unroll
        for (int off = 32; off > 0; off >>= 1) sg += __shfl_xor(sg, off);
        if ((tid & 63) == 0) s_rs[tid >> 6] = sg;
        __syncthreads();
        if (tid == 0) gsum[bj] = ((s_rs[0] + s_rs[1]) + s_rs[2]) + s_rs[3];
    }
}

// ---------- K2: SimOTA column via top-k EXTRACTION (dyn_k <= 10 always) ----------
__global__ __launch_bounds__(320) void colmatch_kernel(
    const float* __restrict__ logits, const float* __restrict__ boxes,
    const int* __restrict__ gtcls, const float* __restrict__ gtbox,
    float* __restrict__ costT, unsigned int* __restrict__ matchcol)
{
    int bj = blockIdx.x;
    int b = bj / N_GT;
    int j = bj - b * N_GT;
    int tid = threadIdx.x;
    __shared__ float s_cost[N_PROP];
    __shared__ float s_iou[N_PROP];
    __shared__ float s_gball[N_GT][4];
    __shared__ int s_valid[N_PROP];
    __shared__ unsigned int s_match[10];

    if (tid < N_GT * 4) ((float*)s_gball)[tid] = gtbox[b * N_GT * 4 + tid];
    if (tid < 10) s_match[tid] = 0u;
    __syncthreads();

    int cls_j = gtcls[b * N_GT + j];
    if (tid < N_PROP) {
        int p = tid;
        const float* ap = boxes + (b * N_PROP + p) * 4;
        float a[4] = {ap[0], ap[1], ap[2], ap[3]};
        float cx = (a[0] + a[2]) * 0.5f;
        float cy = (a[1] + a[3]) * 0.5f;
        int any = 0, inb_j = 0;
        for (int q = 0; q < N_GT; q++) {
            const float* g = s_gball[q];
            int in_gt = (cx >= g[0]) & (cx <= g[2]) & (cy >= g[1]) & (cy <= g[3]);
            float gcx = (g[0] + g[2]) * 0.5f;
            float gcy = (g[1] + g[3]) * 0.5f;
            int in_ct = (fabsf(cx - gcx) <= CENTER_R) & (fabsf(cy - gcy) <= CENTER_R);
            any |= in_gt | in_ct;
            if (q == j) inb_j = in_gt & in_ct;
        }
        s_valid[p] = any;
        const float* g = s_gball[j];
        float x = logits[(size_t)(b * N_PROP + p) * N_CLS + cls_j];
        float pr = 1.f / (1.f + expf(-x));
        float neg = (-logf(1.f - pr + EPSV)) * (1.f - ALPHA) * (pr * pr);
        float pos = (-logf(pr + EPSV)) * ALPHA * ((1.f - pr) * (1.f - pr));
        float clsc = 2.0f * (pos - neg);
        float nb[4], ng[4];
        for (int k = 0; k < 4; k++) { nb[k] = a[k] / S_IMG; ng[k] = g[k] / S_IMG; }
        float l1 = 5.0f * (((fabsf(nb[0] - ng[0]) + fabsf(nb[1] - ng[1]))
                            + fabsf(nb[2] - ng[2])) + fabsf(nb[3] - ng[3]));
        float ngiou = giou_pair(nb, ng);
        float cst = clsc + l1;
        cst = cst + 2.0f * (1.f - ngiou);
        cst = cst + (inb_j ? 0.f : 1e5f);
        cst = cst + (any ? 0.f : 1e9f);
        s_cost[p] = cst;
        costT[(size_t)(b * N_PROP + p) * N_GT + j] = cst;   // proposal-major
        s_iou[p] = any ? iou_unnorm(a, s_gball[j]) : 0.f;
    }
    __syncthreads();

    if (tid < 64) {
        int lane = tid;
        // --- dyn_k: sum of top-10 ious via 10 wave-argmax extractions ---
        float iv[5]; int ii[5];
        #pragma unroll
        for (int c = 0; c < 5; c++) {
            int idx = c * 64 + lane;
            iv[c] = (idx < N_PROP) ? s_iou[idx] : -1.f;
            ii[c] = idx;
        }
        float ksum = 0.f;
        #pragma unroll
        for (int t = 0; t < CAND_K; t++) {
            float bv = iv[0]; int bi = ii[0];
            #pragma unroll
            for (int c = 1; c < 5; c++)
                if (iv[c] > bv || (iv[c] == bv && ii[c] < bi)) { bv = iv[c]; bi = ii[c]; }
            #pragma unroll
            for (int off = 1; off < 64; off <<= 1) {
                float ov = __shfl_xor(bv, off);
                int oi = __shfl_xor(bi, off);
                if (ov > bv || (ov == bv && oi < bi)) { bv = ov; bi = oi; }
            }
            ksum += bv;
            #pragma unroll
            for (int c = 0; c < 5; c++) if (ii[c] == bi) iv[c] = -1.f;
        }
        int dynk = max(1, min((int)ksum, N_PROP));   // <= CAND_K by construction

        // --- match bits: dynk x wave-argmin lex (cost, index) = ranks 0..dynk-1 ---
        float cv[5]; int ci[5];
        #pragma unroll
        for (int c = 0; c < 5; c++) {
            int idx = c * 64 + lane;
            cv[c] = (idx < N_PROP) ? s_cost[idx] : 3e38f;
            ci[c] = idx;
        }
        for (int t = 0; t < dynk; t++) {
            float bv = cv[0]; int bi = ci[0];
            #pragma unroll
            for (int c = 1; c < 5; c++)
                if (cv[c] < bv || (cv[c] == bv && ci[c] < bi)) { bv = cv[c]; bi = ci[c]; }
            #pragma unroll
            for (int off = 1; off < 64; off <<= 1) {
                float ov = __shfl_xor(bv, off);
                int oi = __shfl_xor(bi, off);
                if (ov < bv || (ov == bv && oi < bi)) { bv = ov; bi = oi; }
            }
            if (lane == 0 && s_valid[bi])
                s_match[bi >> 5] |= 1u << (bi & 31);
            #pragma unroll
            for (int c = 0; c < 5; c++) if (ci[c] == bi) cv[c] = 3e38f;
        }
    }
    __syncthreads();
    if (tid < 10) matchcol[bj * 10 + tid] = s_match[tid];
}

// ---------- K3: per-proposal resolve + cls + dice; LAST BLOCK reduces to out ----------
__global__ __launch_bounds__(256) void final_kernel(
    const float* __restrict__ logits, const float* __restrict__ boxes,
    const int* __restrict__ gtcls, const float* __restrict__ gtbox,
    const float* __restrict__ costT, const unsigned int* __restrict__ matchcol,
    const float* __restrict__ proj, const float* __restrict__ gcrop,
    const float* __restrict__ gsum, float* __restrict__ part,
    int* __restrict__ cnt, float* __restrict__ out)
{
    int e = blockIdx.x;
    int b = e / N_PROP;
    int i = e - b * N_PROP;
    int tid = threadIdx.x;

    __shared__ int s_gi, s_any;
    __shared__ float s_l1, s_gl;
    __shared__ float4 s_red[4];
    __shared__ int s_last;
    __shared__ float s_fin[4][5];

    if (tid < 64) {
        int lane = tid;
        float4 a4 = ((const float4*)boxes)[e];
        int ql = (lane < N_GT) ? lane : 0;
        float4 g4 = ((const float4*)gtbox)[b * N_GT + ql];

        float cx = (a4.x + a4.z) * 0.5f;
        float cy = (a4.y + a4.w) * 0.5f;
        int vb = 0;
        if (lane < N_GT) {
            int in_gt = (cx >= g4.x) & (cx <= g4.z) & (cy >= g4.y) & (cy <= g4.w);
            float gcx = (g4.x + g4.z) * 0.5f;
            float gcy = (g4.y + g4.w) * 0.5f;
            int in_ct = (fabsf(cx - gcx) <= CENTER_R) & (fabsf(cy - gcy) <= CENTER_R);
            vb = in_gt | in_ct;
        }
        int any = (__ballot(vb) != 0ULL);

        int gi = 0;
        float l1 = 0.f, gl = 0.f;
        if (any) {
            // resolve only for valid proposals (invalid: outputs independent of gi)
            float cv = 3e38f;
            int idx = 63;
            if (lane < N_GT) { cv = costT[(size_t)e * N_GT + lane]; idx = lane; }
            #pragma unroll
            for (int off = 1; off < 64; off <<= 1) {
                float oc = __shfl_xor(cv, off);
                int oi = __shfl_xor(idx, off);
                if (oc < cv || (oc == cv && oi < idx)) { cv = oc; idx = oi; }
            }
            int best = idx;

            int bit = 0;
            if (lane < N_GT)
                bit = (int)((matchcol[(b * N_GT + lane) * 10 + (i >> 5)] >> (i & 31)) & 1u);
            unsigned long long bm = __ballot(bit);
            int msk = (int)(bm & 0xFFFFFFULL);
            if (__popc(msk) > 1) msk = 1 << best;
            gi = msk ? (__ffs(msk) - 1) : best;

            float gx = __shfl(g4.x, gi), gy = __shfl(g4.y, gi);
            float gz = __shfl(g4.z, gi), gw = __shfl(g4.w, gi);
            float nb[4] = {a4.x / S_IMG, a4.y / S_IMG, a4.z / S_IMG, a4.w / S_IMG};
            float ng[4] = {gx / S_IMG, gy / S_IMG, gz / S_IMG, gw / S_IMG};
            l1 = (((fabsf(nb[0] - ng[0]) + fabsf(nb[1] - ng[1]))
                   + fabsf(nb[2] - ng[2])) + fabsf(nb[3] - ng[3]));
            gl = 1.f - giou_pair(nb, ng);
        }
        if (lane == 0) {
            s_gi = gi; s_any = any; s_l1 = l1; s_gl = gl;
        }
    }
    __syncthreads();

    int gi = s_gi;
    int any = s_any;
    float w = any ? 1.f : 0.f;

    // focal cls: always (invalid -> all-zero labels, mc irrelevant since w=0)
    int mc = gtcls[b * N_GT + gi];
    float clsv = 0.f;
    if (tid < N_CLS)
        clsv = focal_term(logits[(size_t)e * N_CLS + tid], (tid == mc) ? w : 0.f);

    // mask dice (direct proj/gcrop reads; maps L2-hot, ~12 blocks reuse each)
    float inter = 0.f, sp = 0.f;
    if (any) {
        float4 a4 = ((const float4*)boxes)[e];
        const float* pimg = proj + (size_t)(b * N_GT + gi) * (HF * HF);
        const float* gcr = gcrop + (size_t)(b * N_GT + gi) * (TT * TT);
        const float fs = 64.0f / 896.0f;
        float px1 = a4.x * fs, py1 = a4.y * fs, px2 = a4.z * fs, py2 = a4.w * fs;
        #pragma unroll 4
        for (int t = tid; t < TT * TT; t += 256) {
            int ty = t / TT, tx = t - ty * TT;
            float qx = ((float)tx + 0.5f) / (float)TT;
            float qy = ((float)ty + 0.5f) / (float)TT;
            float X = px1 + (px2 - px1) * qx - 0.5f;
            float Y = py1 + (py2 - py1) * qy - 0.5f;
            float lg = bilin(pimg, HF, HF, X, Y);
            float mp = 1.f / (1.f + expf(-lg));
            inter += mp * gcr[t];
            sp += mp;
        }
    }

    #pragma unroll
    for (int off = 32; off > 0; off >>= 1) {
        clsv  += __shfl_xor(clsv, off);
        inter += __shfl_xor(inter, off);
        sp    += __shfl_xor(sp, off);
    }
    if ((tid & 63) == 0) s_red[tid >> 6] = make_float4(clsv, inter, sp, 0.f);
    __syncthreads();
    if (tid == 0) {
        float4 t = s_red[0];
        for (int k = 1; k < 4; k++) {
            t.x += s_red[k].x; t.y += s_red[k].y; t.z += s_red[k].z;
        }
        float sg = any ? gsum[b * N_GT + gi] : 0.f;
        float mterm = any ? (1.f - 2.f * t.y / (t.z + sg + EPSV)) * w : 0.f;
        float* pp = part + (size_t)e * 8;
        *(float4*)pp = make_float4(t.x, any ? s_l1 : 0.f, any ? s_gl : 0.f, mterm);
        pp[4] = w;
    }

    // ---- last-block final reduction (rocPRIM pattern) ----
    __threadfence();
    if (tid == 0) {
        int old = atomicAdd(cnt, 1);
        s_last = (old == N_B * N_PROP - 1);
    }
    __syncthreads();
    if (s_last) {
        __threadfence();
        float s0 = 0.f, s1 = 0.f, s2 = 0.f, s3 = 0.f, s4 = 0.f;
        for (int p = tid; p < N_B * N_PROP; p += 256) {
            const float* pp = part + (size_t)p * 8;
            float4 v = *(const float4*)pp;
            s0 += v.x; s1 += v.y; s2 += v.z; s3 += v.w; s4 += pp[4];
        }
        #pragma unroll
        for (int off = 32; off > 0; off >>= 1) {
            s0 += __shfl_xor(s0, off);
            s1 += __shfl_xor(s1, off);
            s2 += __shfl_xor(s2, off);
            s3 += __shfl_xor(s3, off);
            s4 += __shfl_xor(s4, off);
        }
        if ((tid & 63) == 0) {
            int wv = tid >> 6;
            s_fin[wv][0] = s0; s_fin[wv][1] = s1; s_fin[wv][2] = s2;
            s_fin[wv][3] = s3; s_fin[wv][4] = s4;
        }
        __syncthreads();
        if (tid == 0) {
            float t0 = 0.f, t1 = 0.f, t2 = 0.f, t3 = 0.f, t4 = 0.f;
            for (int k = 0; k < 4; k++) {
                t0 += s_fin[k][0]; t1 += s_fin[k][1]; t2 += s_fin[k][2];
                t3 += s_fin[k][3]; t4 += s_fin[k][4];
            }
            out[0] = 2.0f * t0 / t4;
            out[1] = 5.0f * t1 / t4;
            out[2] = 2.0f * t2 / t4;
            out[3] = 5.0f * t3 / t4;
        }
    }
}

// ---------- launch ----------

extern "C" void kernel_launch(void* const* d_in, const int* in_sizes, int n_in,
                              void* d_out, int out_size, void* d_ws, size_t ws_size,
                              hipStream_t stream)
{
    const float* logits = (const float*)d_in[0];
    const float* boxes  = (const float*)d_in[1];
    const float* feat   = (const float*)d_in[2];
    const float* wm     = (const float*)d_in[3];
    const int*   gtcls  = (const int*)d_in[4];
    const float* gtbox  = (const float*)d_in[5];
    const float* gmask  = (const float*)d_in[6];
    float* out = (float*)d_out;
    float* ws  = (float*)d_ws;

    float* costT = ws;                                        // 28800 floats
    unsigned int* matchcol = (unsigned int*)(ws + 28800);     // 960 u32
    float* part  = ws + 28800 + 960;                          // 9600 floats
    float* proj  = ws + 28800 + 960 + 9600;                   // 393216 floats
    float* gcrop = proj + 393216;                             // 75264 floats
    float* gsum  = gcrop + 75264;                             // 96 floats
    int*   cnt   = (int*)(gsum + 96);                         // 1 int

    hipLaunchKernelGGL(prep_kernel, dim3(256 + N_B * N_GT), dim3(256), 0, stream,
                       feat, wm, gtcls, gtbox, gmask, proj, gcrop, gsum, cnt);
    hipLaunchKernelGGL(colmatch_kernel, dim3(N_B * N_GT), dim3(320), 0, stream,
                       logits, boxes, gtcls, gtbox, costT, matchcol);
    hipLaunchKernelGGL(final_kernel, dim3(N_B * N_PROP), dim3(256), 0, stream,
                       logits, boxes, gtcls, gtbox, costT, matchcol, proj, gcrop,
                       gsum, part, cnt, out);
}

// Round 10
// 109.205 us; speedup vs baseline: 1.8355x; 1.8355x over previous
//
#include <hip/hip_runtime.h>
#include <math.h>

#define N_PROP 300
#define N_CLS  80
#define N_GT   24
#define N_B    4
#define CF     128
#define HF     64
#define HM     224
#define TT     28
#define ALPHA  0.25f
#define EPSV   1e-8f
#define CAND_K 10
#define CENTER_R 44.8f
#define S_IMG 896.0f

// ---------- device helpers ----------

__device__ __forceinline__ float iou_unnorm(const float* a, const float* g) {
    float lx = fmaxf(a[0], g[0]), ly = fmaxf(a[1], g[1]);
    float rx = fminf(a[2], g[2]), ry = fminf(a[3], g[3]);
    float w = fmaxf(rx - lx, 0.f), h = fmaxf(ry - ly, 0.f);
    float inter = w * h;
    float aa = fmaxf(a[2] - a[0], 0.f) * fmaxf(a[3] - a[1], 0.f);
    float ag = fmaxf(g[2] - g[0], 0.f) * fmaxf(g[3] - g[1], 0.f);
    float uni = aa + ag - inter;
    return inter / (uni + EPSV);
}

__device__ __forceinline__ float giou_pair(const float* a, const float* g) {
    float lx = fmaxf(a[0], g[0]), ly = fmaxf(a[1], g[1]);
    float rx = fminf(a[2], g[2]), ry = fminf(a[3], g[3]);
    float w = fmaxf(rx - lx, 0.f), h = fmaxf(ry - ly, 0.f);
    float inter = w * h;
    float aa = fmaxf(a[2] - a[0], 0.f) * fmaxf(a[3] - a[1], 0.f);
    float ag = fmaxf(g[2] - g[0], 0.f) * fmaxf(g[3] - g[1], 0.f);
    float uni = aa + ag - inter;
    float iou = inter / (uni + EPSV);
    float elx = fminf(a[0], g[0]), ely = fminf(a[1], g[1]);
    float erx = fmaxf(a[2], g[2]), ery = fmaxf(a[3], g[3]);
    float ew = fmaxf(erx - elx, 0.f), eh = fmaxf(ery - ely, 0.f);
    float enc = ew * eh;
    return iou - (enc - uni) / (enc + EPSV);
}

__device__ __forceinline__ float bilin(const float* img, int H, int W, float X, float Y) {
    float x0f = fminf(fmaxf(floorf(X), 0.f), (float)(W - 1));
    float y0f = fminf(fmaxf(floorf(Y), 0.f), (float)(H - 1));
    float wx = fminf(fmaxf(X - x0f, 0.f), 1.f);
    float wy = fminf(fmaxf(Y - y0f, 0.f), 1.f);
    int x0 = (int)x0f, y0 = (int)y0f;
    int x1 = min(x0 + 1, W - 1), y1 = min(y0 + 1, H - 1);
    float v00 = img[y0 * W + x0], v01 = img[y0 * W + x1];
    float v10 = img[y1 * W + x0], v11 = img[y1 * W + x1];
    return v00 * (1.f - wx) * (1.f - wy) + v01 * wx * (1.f - wy)
         + v10 * (1.f - wx) * wy + v11 * wx * wy;
}

__device__ __forceinline__ float focal_term(float x, float label) {
    float p = 1.f / (1.f + expf(-x));
    float ce = fmaxf(x, 0.f) + log1pf(expf(-fabsf(x))) - x * label;
    float pt = p * label + (1.f - p) * (1.f - label);
    float at = ALPHA * label + (1.f - ALPHA) * (1.f - label);
    return at * (1.f - pt) * (1.f - pt) * ce;
}

// ---------- K1: fused prep + colmatch (independent roles, one dispatch) ----------
// blocks [0,256): proj; [256,352): gcrop; [352,448): colmatch column.
__global__ __launch_bounds__(256) void prep_kernel(
    const float* __restrict__ feat, const float* __restrict__ wm,
    const float* __restrict__ logits, const float* __restrict__ boxes,
    const int* __restrict__ gtcls, const float* __restrict__ gtbox,
    const float* __restrict__ gmask, float* __restrict__ proj,
    float* __restrict__ gcrop, float* __restrict__ gsum,
    float* __restrict__ costT, unsigned int* __restrict__ matchcol)
{
    int blk = blockIdx.x;
    int tid = threadIdx.x;

    // proj-role LDS
    __shared__ __align__(16) float s_w[CF][N_GT];       // 12 KB
    __shared__ float s_acc[4][64][N_GT + 1];            // 25.6 KB
    // colmatch-role LDS
    __shared__ float s_cost[N_PROP];
    __shared__ float s_iou[N_PROP];
    __shared__ float s_gball[N_GT][4];
    __shared__ int s_valid[N_PROP];
    __shared__ unsigned int s_match[10];
    __shared__ float s_rs[4];

    if (blk < 256) {
        // ---------------- proj role ----------------
        int b = blk >> 6;
        int chunk = blk & 63;
        for (int k = tid; k < N_GT * CF; k += 256) {
            int j = k >> 7, f = k & 127;
            s_w[f][j] = wm[gtcls[b * N_GT + j] * CF + f];
        }
        __syncthreads();

        int px = tid & 63;
        int fq = tid >> 6;
        int pix = chunk * 64 + px;
        const float* fb = feat + ((size_t)b * CF + fq * 32) * (HF * HF) + pix;
        float accv[N_GT];
        #pragma unroll
        for (int j = 0; j < N_GT; j++) accv[j] = 0.f;
        #pragma unroll 8
        for (int f = 0; f < 32; f++) {
            float v = fb[(size_t)f * HF * HF];
            const float4* wrow = (const float4*)&s_w[fq * 32 + f][0];
            #pragma unroll
            for (int q = 0; q < 6; q++) {
                float4 wv = wrow[q];
                accv[q * 4 + 0] = fmaf(wv.x, v, accv[q * 4 + 0]);
                accv[q * 4 + 1] = fmaf(wv.y, v, accv[q * 4 + 1]);
                accv[q * 4 + 2] = fmaf(wv.z, v, accv[q * 4 + 2]);
                accv[q * 4 + 3] = fmaf(wv.w, v, accv[q * 4 + 3]);
            }
        }
        #pragma unroll
        for (int j = 0; j < N_GT; j++) s_acc[fq][px][j] = accv[j];
        __syncthreads();
        for (int o = tid; o < 64 * N_GT; o += 256) {
            int j = o >> 6, p2 = o & 63;
            float s = s_acc[0][p2][j] + s_acc[1][p2][j] + s_acc[2][p2][j] + s_acc[3][p2][j];
            proj[(size_t)(b * N_GT + j) * (HF * HF) + chunk * 64 + p2] = s;
        }
    } else if (blk < 352) {
        // ---------------- gcrop role: one block per (b, j) ----------------
        int bj = blk - 256;
        int b = bj / N_GT;
        int j = bj - b * N_GT;
        const float* gimg = gmask + (size_t)(b * N_GT + j) * HM * HM;
        float4 g4 = ((const float4*)gtbox)[b * N_GT + j];
        const float ms = 224.0f / 896.0f;
        float gx1 = g4.x * ms, gy1 = g4.y * ms, gx2 = g4.z * ms, gy2 = g4.w * ms;
        float sg = 0.f;
        #pragma unroll 4
        for (int t = tid; t < TT * TT; t += 256) {
            int ty = t / TT, tx = t - ty * TT;
            float qx = ((float)tx + 0.5f) / (float)TT;
            float qy = ((float)ty + 0.5f) / (float)TT;
            float Xg = gx1 + (gx2 - gx1) * qx - 0.5f;
            float Yg = gy1 + (gy2 - gy1) * qy - 0.5f;
            float gc = bilin(gimg, HM, HM, Xg, Yg);
            gcrop[(size_t)bj * (TT * TT) + t] = gc;
            sg += gc;
        }
        #pragma unroll
        for (int off = 32; off > 0; off >>= 1) sg += __shfl_xor(sg, off);
        if ((tid & 63) == 0) s_rs[tid >> 6] = sg;
        __syncthreads();
        if (tid == 0) gsum[bj] = ((s_rs[0] + s_rs[1]) + s_rs[2]) + s_rs[3];
    } else {
        // ---------------- colmatch role: one block per (b, j) ----------------
        int bj = blk - 352;
        int b = bj / N_GT;
        int j = bj - b * N_GT;

        if (tid < N_GT * 4) ((float*)s_gball)[tid] = gtbox[b * N_GT * 4 + tid];
        if (tid < 10) s_match[tid] = 0u;
        __syncthreads();

        int cls_j = gtcls[b * N_GT + j];
        for (int p = tid; p < N_PROP; p += 256) {
            const float* ap = boxes + (b * N_PROP + p) * 4;
            float a[4] = {ap[0], ap[1], ap[2], ap[3]};
            float cx = (a[0] + a[2]) * 0.5f;
            float cy = (a[1] + a[3]) * 0.5f;
            int any = 0, inb_j = 0;
            for (int q = 0; q < N_GT; q++) {
                const float* g = s_gball[q];
                int in_gt = (cx >= g[0]) & (cx <= g[2]) & (cy >= g[1]) & (cy <= g[3]);
                float gcx = (g[0] + g[2]) * 0.5f;
                float gcy = (g[1] + g[3]) * 0.5f;
                int in_ct = (fabsf(cx - gcx) <= CENTER_R) & (fabsf(cy - gcy) <= CENTER_R);
                any |= in_gt | in_ct;
                if (q == j) inb_j = in_gt & in_ct;
            }
            s_valid[p] = any;
            const float* g = s_gball[j];
            float x = logits[(size_t)(b * N_PROP + p) * N_CLS + cls_j];
            float pr = 1.f / (1.f + expf(-x));
            float neg = (-logf(1.f - pr + EPSV)) * (1.f - ALPHA) * (pr * pr);
            float pos = (-logf(pr + EPSV)) * ALPHA * ((1.f - pr) * (1.f - pr));
            float clsc = 2.0f * (pos - neg);
            float nb[4], ng[4];
            for (int k = 0; k < 4; k++) { nb[k] = a[k] / S_IMG; ng[k] = g[k] / S_IMG; }
            float l1 = 5.0f * (((fabsf(nb[0] - ng[0]) + fabsf(nb[1] - ng[1]))
                                + fabsf(nb[2] - ng[2])) + fabsf(nb[3] - ng[3]));
            float ngiou = giou_pair(nb, ng);
            float cst = clsc + l1;
            cst = cst + 2.0f * (1.f - ngiou);
            cst = cst + (inb_j ? 0.f : 1e5f);
            cst = cst + (any ? 0.f : 1e9f);
            s_cost[p] = cst;
            costT[(size_t)(b * N_PROP + p) * N_GT + j] = cst;   // proposal-major
            s_iou[p] = any ? iou_unnorm(a, s_gball[j]) : 0.f;
        }
        __syncthreads();

        if (tid < 64) {
            int lane = tid;
            // dyn_k: sum of top-10 ious via 10 wave-argmax extractions
            float iv[5]; int ii[5];
            #pragma unroll
            for (int c = 0; c < 5; c++) {
                int idx = c * 64 + lane;
                iv[c] = (idx < N_PROP) ? s_iou[idx] : -1.f;
                ii[c] = idx;
            }
            float ksum = 0.f;
            #pragma unroll
            for (int t = 0; t < CAND_K; t++) {
                float bv = iv[0]; int bi = ii[0];
                #pragma unroll
                for (int c = 1; c < 5; c++)
                    if (iv[c] > bv || (iv[c] == bv && ii[c] < bi)) { bv = iv[c]; bi = ii[c]; }
                #pragma unroll
                for (int off = 1; off < 64; off <<= 1) {
                    float ov = __shfl_xor(bv, off);
                    int oi = __shfl_xor(bi, off);
                    if (ov > bv || (ov == bv && oi < bi)) { bv = ov; bi = oi; }
                }
                ksum += bv;
                #pragma unroll
                for (int c = 0; c < 5; c++) if (ii[c] == bi) iv[c] = -1.f;
            }
            int dynk = max(1, min((int)ksum, N_PROP));

            // match bits: dynk x wave-argmin lex (cost, index) = ranks 0..dynk-1
            float cv[5]; int ci[5];
            #pragma unroll
            for (int c = 0; c < 5; c++) {
                int idx = c * 64 + lane;
                cv[c] = (idx < N_PROP) ? s_cost[idx] : 3e38f;
                ci[c] = idx;
            }
            for (int t = 0; t < dynk; t++) {
                float bv = cv[0]; int bi = ci[0];
                #pragma unroll
                for (int c = 1; c < 5; c++)
                    if (cv[c] < bv || (cv[c] == bv && ci[c] < bi)) { bv = cv[c]; bi = ci[c]; }
                #pragma unroll
                for (int off = 1; off < 64; off <<= 1) {
                    float ov = __shfl_xor(bv, off);
                    int oi = __shfl_xor(bi, off);
                    if (ov < bv || (ov == bv && oi < bi)) { bv = ov; bi = oi; }
                }
                if (lane == 0 && s_valid[bi])
                    s_match[bi >> 5] |= 1u << (bi & 31);
                #pragma unroll
                for (int c = 0; c < 5; c++) if (ci[c] == bi) cv[c] = 3e38f;
            }
        }
        __syncthreads();
        if (tid < 10) matchcol[bj * 10 + tid] = s_match[tid];
    }
}

// ---------- K2: per-proposal resolve + cls + dice; plain part stores ----------
__global__ __launch_bounds__(256) void final_kernel(
    const float* __restrict__ logits, const float* __restrict__ boxes,
    const int* __restrict__ gtcls, const float* __restrict__ gtbox,
    const float* __restrict__ costT, const unsigned int* __restrict__ matchcol,
    const float* __restrict__ proj, const float* __restrict__ gcrop,
    const float* __restrict__ gsum, float* __restrict__ part)
{
    int e = blockIdx.x;
    int b = e / N_PROP;
    int i = e - b * N_PROP;
    int tid = threadIdx.x;

    __shared__ int s_gi, s_any;
    __shared__ float s_l1, s_gl;
    __shared__ float4 s_red[4];

    if (tid < 64) {
        int lane = tid;
        float4 a4 = ((const float4*)boxes)[e];
        int ql = (lane < N_GT) ? lane : 0;
        float4 g4 = ((const float4*)gtbox)[b * N_GT + ql];

        float cx = (a4.x + a4.z) * 0.5f;
        float cy = (a4.y + a4.w) * 0.5f;
        int vb = 0;
        if (lane < N_GT) {
            int in_gt = (cx >= g4.x) & (cx <= g4.z) & (cy >= g4.y) & (cy <= g4.w);
            float gcx = (g4.x + g4.z) * 0.5f;
            float gcy = (g4.y + g4.w) * 0.5f;
            int in_ct = (fabsf(cx - gcx) <= CENTER_R) & (fabsf(cy - gcy) <= CENTER_R);
            vb = in_gt | in_ct;
        }
        int any = (__ballot(vb) != 0ULL);

        int gi = 0;
        float l1 = 0.f, gl = 0.f;
        if (any) {
            // resolve only for valid proposals (invalid: outputs independent of gi)
            float cv = 3e38f;
            int idx = 63;
            if (lane < N_GT) { cv = costT[(size_t)e * N_GT + lane]; idx = lane; }
            #pragma unroll
            for (int off = 1; off < 64; off <<= 1) {
                float oc = __shfl_xor(cv, off);
                int oi = __shfl_xor(idx, off);
                if (oc < cv || (oc == cv && oi < idx)) { cv = oc; idx = oi; }
            }
            int best = idx;

            int bit = 0;
            if (lane < N_GT)
                bit = (int)((matchcol[(b * N_GT + lane) * 10 + (i >> 5)] >> (i & 31)) & 1u);
            unsigned long long bm = __ballot(bit);
            int msk = (int)(bm & 0xFFFFFFULL);
            if (__popc(msk) > 1) msk = 1 << best;
            gi = msk ? (__ffs(msk) - 1) : best;

            float gx = __shfl(g4.x, gi), gy = __shfl(g4.y, gi);
            float gz = __shfl(g4.z, gi), gw = __shfl(g4.w, gi);
            float nb[4] = {a4.x / S_IMG, a4.y / S_IMG, a4.z / S_IMG, a4.w / S_IMG};
            float ng[4] = {gx / S_IMG, gy / S_IMG, gz / S_IMG, gw / S_IMG};
            l1 = (((fabsf(nb[0] - ng[0]) + fabsf(nb[1] - ng[1]))
                   + fabsf(nb[2] - ng[2])) + fabsf(nb[3] - ng[3]));
            gl = 1.f - giou_pair(nb, ng);
        }
        if (lane == 0) {
            s_gi = gi; s_any = any; s_l1 = l1; s_gl = gl;
        }
    }
    __syncthreads();

    int gi = s_gi;
    int any = s_any;
    float w = any ? 1.f : 0.f;

    // focal cls: always (invalid -> all-zero labels, mc irrelevant since w=0)
    int mc = gtcls[b * N_GT + gi];
    float clsv = 0.f;
    if (tid < N_CLS)
        clsv = focal_term(logits[(size_t)e * N_CLS + tid], (tid == mc) ? w : 0.f);

    // mask dice (direct proj/gcrop reads; maps L2-hot, ~12 blocks reuse each)
    float inter = 0.f, sp = 0.f;
    if (any) {
        float4 a4 = ((const float4*)boxes)[e];
        const float* pimg = proj + (size_t)(b * N_GT + gi) * (HF * HF);
        const float* gcr = gcrop + (size_t)(b * N_GT + gi) * (TT * TT);
        const float fs = 64.0f / 896.0f;
        float px1 = a4.x * fs, py1 = a4.y * fs, px2 = a4.z * fs, py2 = a4.w * fs;
        #pragma unroll 4
        for (int t = tid; t < TT * TT; t += 256) {
            int ty = t / TT, tx = t - ty * TT;
            float qx = ((float)tx + 0.5f) / (float)TT;
            float qy = ((float)ty + 0.5f) / (float)TT;
            float X = px1 + (px2 - px1) * qx - 0.5f;
            float Y = py1 + (py2 - py1) * qy - 0.5f;
            float lg = bilin(pimg, HF, HF, X, Y);
            float mp = 1.f / (1.f + expf(-lg));
            inter += mp * gcr[t];
            sp += mp;
        }
    }

    #pragma unroll
    for (int off = 32; off > 0; off >>= 1) {
        clsv  += __shfl_xor(clsv, off);
        inter += __shfl_xor(inter, off);
        sp    += __shfl_xor(sp, off);
    }
    if ((tid & 63) == 0) s_red[tid >> 6] = make_float4(clsv, inter, sp, 0.f);
    __syncthreads();
    if (tid == 0) {
        float4 t = s_red[0];
        for (int k = 1; k < 4; k++) {
            t.x += s_red[k].x; t.y += s_red[k].y; t.z += s_red[k].z;
        }
        float sg = any ? gsum[b * N_GT + gi] : 0.f;
        float mterm = any ? (1.f - 2.f * t.y / (t.z + sg + EPSV)) * w : 0.f;
        float* pp = part + (size_t)e * 8;
        *(float4*)pp = make_float4(t.x, any ? s_l1 : 0.f, any ? s_gl : 0.f, mterm);
        pp[4] = w;
    }
}

// ---------- K3: reduce 1200x5 partials -> 4 outputs (single block) ----------
__global__ __launch_bounds__(256) void fin_kernel(
    const float* __restrict__ part, float* __restrict__ out)
{
    int tid = threadIdx.x;
    __shared__ float s_red[4][5];
    float s0 = 0.f, s1 = 0.f, s2 = 0.f, s3 = 0.f, s4 = 0.f;
    for (int p = tid; p < N_B * N_PROP; p += 256) {
        const float* pp = part + (size_t)p * 8;
        float4 v = *(const float4*)pp;
        s0 += v.x; s1 += v.y; s2 += v.z; s3 += v.w; s4 += pp[4];
    }
    #pragma unroll
    for (int off = 32; off > 0; off >>= 1) {
        s0 += __shfl_xor(s0, off);
        s1 += __shfl_xor(s1, off);
        s2 += __shfl_xor(s2, off);
        s3 += __shfl_xor(s3, off);
        s4 += __shfl_xor(s4, off);
    }
    if ((tid & 63) == 0) {
        int wv = tid >> 6;
        s_red[wv][0] = s0; s_red[wv][1] = s1; s_red[wv][2] = s2;
        s_red[wv][3] = s3; s_red[wv][4] = s4;
    }
    __syncthreads();
    if (tid == 0) {
        float t0 = 0.f, t1 = 0.f, t2 = 0.f, t3 = 0.f, t4 = 0.f;
        for (int k = 0; k < 4; k++) {
            t0 += s_red[k][0]; t1 += s_red[k][1]; t2 += s_red[k][2];
            t3 += s_red[k][3]; t4 += s_red[k][4];
        }
        out[0] = 2.0f * t0 / t4;
        out[1] = 5.0f * t1 / t4;
        out[2] = 2.0f * t2 / t4;
        out[3] = 5.0f * t3 / t4;
    }
}

// ---------- launch ----------

extern "C" void kernel_launch(void* const* d_in, const int* in_sizes, int n_in,
                              void* d_out, int out_size, void* d_ws, size_t ws_size,
                              hipStream_t stream)
{
    const float* logits = (const float*)d_in[0];
    const float* boxes  = (const float*)d_in[1];
    const float* feat   = (const float*)d_in[2];
    const float* wm     = (const float*)d_in[3];
    const int*   gtcls  = (const int*)d_in[4];
    const float* gtbox  = (const float*)d_in[5];
    const float* gmask  = (const float*)d_in[6];
    float* out = (float*)d_out;
    float* ws  = (float*)d_ws;

    float* costT = ws;                                        // 28800 floats
    unsigned int* matchcol = (unsigned int*)(ws + 28800);     // 960 u32
    float* part  = ws + 28800 + 960;                          // 9600 floats
    float* proj  = ws + 28800 + 960 + 9600;                   // 393216 floats
    float* gcrop = proj + 393216;                             // 75264 floats
    float* gsum  = gcrop + 75264;                             // 96 floats

    hipLaunchKernelGGL(prep_kernel, dim3(256 + 96 + 96), dim3(256), 0, stream,
                       feat, wm, logits, boxes, gtcls, gtbox, gmask,
                       proj, gcrop, gsum, costT, matchcol);
    hipLaunchKernelGGL(final_kernel, dim3(N_B * N_PROP), dim3(256), 0, stream,
                       logits, boxes, gtcls, gtbox, costT, matchcol, proj, gcrop,
                       gsum, part);
    hipLaunchKernelGGL(fin_kernel, dim3(1), dim3(256), 0, stream, part, out);
}

// Round 11
// 108.846 us; speedup vs baseline: 1.8415x; 1.0033x over previous
//
#include <hip/hip_runtime.h>
#include <math.h>

#define N_PROP 300
#define N_CLS  80
#define N_GT   24
#define N_B    4
#define CF     128
#define HF     64
#define HM     224
#define TT     28
#define ALPHA  0.25f
#define EPSV   1e-8f
#define CAND_K 10
#define CENTER_R 44.8f
#define S_IMG 896.0f

// ---------- device helpers ----------

__device__ __forceinline__ float iou_unnorm(const float* a, const float* g) {
    float lx = fmaxf(a[0], g[0]), ly = fmaxf(a[1], g[1]);
    float rx = fminf(a[2], g[2]), ry = fminf(a[3], g[3]);
    float w = fmaxf(rx - lx, 0.f), h = fmaxf(ry - ly, 0.f);
    float inter = w * h;
    float aa = fmaxf(a[2] - a[0], 0.f) * fmaxf(a[3] - a[1], 0.f);
    float ag = fmaxf(g[2] - g[0], 0.f) * fmaxf(g[3] - g[1], 0.f);
    float uni = aa + ag - inter;
    return inter / (uni + EPSV);
}

__device__ __forceinline__ float giou_pair(const float* a, const float* g) {
    float lx = fmaxf(a[0], g[0]), ly = fmaxf(a[1], g[1]);
    float rx = fminf(a[2], g[2]), ry = fminf(a[3], g[3]);
    float w = fmaxf(rx - lx, 0.f), h = fmaxf(ry - ly, 0.f);
    float inter = w * h;
    float aa = fmaxf(a[2] - a[0], 0.f) * fmaxf(a[3] - a[1], 0.f);
    float ag = fmaxf(g[2] - g[0], 0.f) * fmaxf(g[3] - g[1], 0.f);
    float uni = aa + ag - inter;
    float iou = inter / (uni + EPSV);
    float elx = fminf(a[0], g[0]), ely = fminf(a[1], g[1]);
    float erx = fmaxf(a[2], g[2]), ery = fmaxf(a[3], g[3]);
    float ew = fmaxf(erx - elx, 0.f), eh = fmaxf(ery - ely, 0.f);
    float enc = ew * eh;
    return iou - (enc - uni) / (enc + EPSV);
}

__device__ __forceinline__ float bilin(const float* img, int H, int W, float X, float Y) {
    float x0f = fminf(fmaxf(floorf(X), 0.f), (float)(W - 1));
    float y0f = fminf(fmaxf(floorf(Y), 0.f), (float)(H - 1));
    float wx = fminf(fmaxf(X - x0f, 0.f), 1.f);
    float wy = fminf(fmaxf(Y - y0f, 0.f), 1.f);
    int x0 = (int)x0f, y0 = (int)y0f;
    int x1 = min(x0 + 1, W - 1), y1 = min(y0 + 1, H - 1);
    float v00 = img[y0 * W + x0], v01 = img[y0 * W + x1];
    float v10 = img[y1 * W + x0], v11 = img[y1 * W + x1];
    return v00 * (1.f - wx) * (1.f - wy) + v01 * wx * (1.f - wy)
         + v10 * (1.f - wx) * wy + v11 * wx * wy;
}

__device__ __forceinline__ float focal_term(float x, float label) {
    float p = 1.f / (1.f + expf(-x));
    float ce = fmaxf(x, 0.f) + log1pf(expf(-fabsf(x))) - x * label;
    float pt = p * label + (1.f - p) * (1.f - label);
    float at = ALPHA * label + (1.f - ALPHA) * (1.f - label);
    return at * (1.f - pt) * (1.f - pt) * ce;
}

// ---------- K1: fused colmatch + gcrop + proj (long-latency roles first) ----------
// blocks [0,96): colmatch column; [96,192): gcrop; [192,448): proj.
__global__ __launch_bounds__(256) void prep_kernel(
    const float* __restrict__ feat, const float* __restrict__ wm,
    const float* __restrict__ logits, const float* __restrict__ boxes,
    const int* __restrict__ gtcls, const float* __restrict__ gtbox,
    const float* __restrict__ gmask, float* __restrict__ proj,
    float* __restrict__ gcrop, float* __restrict__ gsum,
    float* __restrict__ costT, unsigned int* __restrict__ matchcol)
{
    int blk = blockIdx.x;
    int tid = threadIdx.x;

    // proj-role LDS
    __shared__ __align__(16) float s_w[CF][N_GT];       // 12 KB
    __shared__ float s_acc[4][64][N_GT + 1];            // 25.6 KB
    // colmatch-role LDS
    __shared__ float s_cost[N_PROP];
    __shared__ float s_iou[N_PROP];
    __shared__ float s_gball[N_GT][4];
    __shared__ int s_valid[N_PROP];
    __shared__ unsigned int s_match[10];
    __shared__ float s_rs[4];

    if (blk < 96) {
        // ---------------- colmatch role: one block per (b, j) ----------------
        int bj = blk;
        int b = bj / N_GT;
        int j = bj - b * N_GT;

        if (tid < N_GT * 4) ((float*)s_gball)[tid] = gtbox[b * N_GT * 4 + tid];
        if (tid < 10) s_match[tid] = 0u;
        __syncthreads();

        int cls_j = gtcls[b * N_GT + j];
        for (int p = tid; p < N_PROP; p += 256) {
            const float* ap = boxes + (b * N_PROP + p) * 4;
            float a[4] = {ap[0], ap[1], ap[2], ap[3]};
            float cx = (a[0] + a[2]) * 0.5f;
            float cy = (a[1] + a[3]) * 0.5f;
            int any = 0, inb_j = 0;
            for (int q = 0; q < N_GT; q++) {
                const float* g = s_gball[q];
                int in_gt = (cx >= g[0]) & (cx <= g[2]) & (cy >= g[1]) & (cy <= g[3]);
                float gcx = (g[0] + g[2]) * 0.5f;
                float gcy = (g[1] + g[3]) * 0.5f;
                int in_ct = (fabsf(cx - gcx) <= CENTER_R) & (fabsf(cy - gcy) <= CENTER_R);
                any |= in_gt | in_ct;
                if (q == j) inb_j = in_gt & in_ct;
            }
            s_valid[p] = any;
            const float* g = s_gball[j];
            float x = logits[(size_t)(b * N_PROP + p) * N_CLS + cls_j];
            float pr = 1.f / (1.f + expf(-x));
            float neg = (-logf(1.f - pr + EPSV)) * (1.f - ALPHA) * (pr * pr);
            float pos = (-logf(pr + EPSV)) * ALPHA * ((1.f - pr) * (1.f - pr));
            float clsc = 2.0f * (pos - neg);
            float nb[4], ng[4];
            for (int k = 0; k < 4; k++) { nb[k] = a[k] / S_IMG; ng[k] = g[k] / S_IMG; }
            float l1 = 5.0f * (((fabsf(nb[0] - ng[0]) + fabsf(nb[1] - ng[1]))
                                + fabsf(nb[2] - ng[2])) + fabsf(nb[3] - ng[3]));
            float ngiou = giou_pair(nb, ng);
            float cst = clsc + l1;
            cst = cst + 2.0f * (1.f - ngiou);
            cst = cst + (inb_j ? 0.f : 1e5f);
            cst = cst + (any ? 0.f : 1e9f);
            s_cost[p] = cst;
            costT[(size_t)(b * N_PROP + p) * N_GT + j] = cst;   // proposal-major
            s_iou[p] = any ? iou_unnorm(a, s_gball[j]) : 0.f;
        }
        __syncthreads();

        if (tid < 64) {
            int lane = tid;
            // dyn_k: sum of top-10 ious via 10 wave-argmax extractions
            float iv[5]; int ii[5];
            #pragma unroll
            for (int c = 0; c < 5; c++) {
                int idx = c * 64 + lane;
                iv[c] = (idx < N_PROP) ? s_iou[idx] : -1.f;
                ii[c] = idx;
            }
            float ksum = 0.f;
            #pragma unroll
            for (int t = 0; t < CAND_K; t++) {
                float bv = iv[0]; int bi = ii[0];
                #pragma unroll
                for (int c = 1; c < 5; c++)
                    if (iv[c] > bv || (iv[c] == bv && ii[c] < bi)) { bv = iv[c]; bi = ii[c]; }
                #pragma unroll
                for (int off = 1; off < 64; off <<= 1) {
                    float ov = __shfl_xor(bv, off);
                    int oi = __shfl_xor(bi, off);
                    if (ov > bv || (ov == bv && oi < bi)) { bv = ov; bi = oi; }
                }
                ksum += bv;
                #pragma unroll
                for (int c = 0; c < 5; c++) if (ii[c] == bi) iv[c] = -1.f;
            }
            int dynk = max(1, min((int)ksum, N_PROP));

            // match bits: dynk x wave-argmin lex (cost, index) = ranks 0..dynk-1
            float cv[5]; int ci[5];
            #pragma unroll
            for (int c = 0; c < 5; c++) {
                int idx = c * 64 + lane;
                cv[c] = (idx < N_PROP) ? s_cost[idx] : 3e38f;
                ci[c] = idx;
            }
            for (int t = 0; t < dynk; t++) {
                float bv = cv[0]; int bi = ci[0];
                #pragma unroll
                for (int c = 1; c < 5; c++)
                    if (cv[c] < bv || (cv[c] == bv && ci[c] < bi)) { bv = cv[c]; bi = ci[c]; }
                #pragma unroll
                for (int off = 1; off < 64; off <<= 1) {
                    float ov = __shfl_xor(bv, off);
                    int oi = __shfl_xor(bi, off);
                    if (ov < bv || (ov == bv && oi < bi)) { bv = ov; bi = oi; }
                }
                if (lane == 0 && s_valid[bi])
                    s_match[bi >> 5] |= 1u << (bi & 31);
                #pragma unroll
                for (int c = 0; c < 5; c++) if (ci[c] == bi) cv[c] = 3e38f;
            }
        }
        __syncthreads();
        if (tid < 10) matchcol[bj * 10 + tid] = s_match[tid];
    } else if (blk < 192) {
        // ---------------- gcrop role: one block per (b, j) ----------------
        int bj = blk - 96;
        int b = bj / N_GT;
        int j = bj - b * N_GT;
        const float* gimg = gmask + (size_t)(b * N_GT + j) * HM * HM;
        float4 g4 = ((const float4*)gtbox)[b * N_GT + j];
        const float ms = 224.0f / 896.0f;
        float gx1 = g4.x * ms, gy1 = g4.y * ms, gx2 = g4.z * ms, gy2 = g4.w * ms;
        float sg = 0.f;
        #pragma unroll 4
        for (int t = tid; t < TT * TT; t += 256) {
            int ty = t / TT, tx = t - ty * TT;
            float qx = ((float)tx + 0.5f) / (float)TT;
            float qy = ((float)ty + 0.5f) / (float)TT;
            float Xg = gx1 + (gx2 - gx1) * qx - 0.5f;
            float Yg = gy1 + (gy2 - gy1) * qy - 0.5f;
            float gc = bilin(gimg, HM, HM, Xg, Yg);
            gcrop[(size_t)bj * (TT * TT) + t] = gc;
            sg += gc;
        }
        #pragma unroll
        for (int off = 32; off > 0; off >>= 1) sg += __shfl_xor(sg, off);
        if ((tid & 63) == 0) s_rs[tid >> 6] = sg;
        __syncthreads();
        if (tid == 0) gsum[bj] = ((s_rs[0] + s_rs[1]) + s_rs[2]) + s_rs[3];
    } else {
        // ---------------- proj role ----------------
        int pb = blk - 192;
        int b = pb >> 6;
        int chunk = pb & 63;
        for (int k = tid; k < N_GT * CF; k += 256) {
            int j = k >> 7, f = k & 127;
            s_w[f][j] = wm[gtcls[b * N_GT + j] * CF + f];
        }
        __syncthreads();

        int px = tid & 63;
        int fq = tid >> 6;
        int pix = chunk * 64 + px;
        const float* fb = feat + ((size_t)b * CF + fq * 32) * (HF * HF) + pix;
        float accv[N_GT];
        #pragma unroll
        for (int j = 0; j < N_GT; j++) accv[j] = 0.f;
        #pragma unroll 8
        for (int f = 0; f < 32; f++) {
            float v = fb[(size_t)f * HF * HF];
            const float4* wrow = (const float4*)&s_w[fq * 32 + f][0];
            #pragma unroll
            for (int q = 0; q < 6; q++) {
                float4 wv = wrow[q];
                accv[q * 4 + 0] = fmaf(wv.x, v, accv[q * 4 + 0]);
                accv[q * 4 + 1] = fmaf(wv.y, v, accv[q * 4 + 1]);
                accv[q * 4 + 2] = fmaf(wv.z, v, accv[q * 4 + 2]);
                accv[q * 4 + 3] = fmaf(wv.w, v, accv[q * 4 + 3]);
            }
        }
        #pragma unroll
        for (int j = 0; j < N_GT; j++) s_acc[fq][px][j] = accv[j];
        __syncthreads();
        for (int o = tid; o < 64 * N_GT; o += 256) {
            int j = o >> 6, p2 = o & 63;
            float s = s_acc[0][p2][j] + s_acc[1][p2][j] + s_acc[2][p2][j] + s_acc[3][p2][j];
            proj[(size_t)(b * N_GT + j) * (HF * HF) + chunk * 64 + p2] = s;
        }
    }
}

// ---------- K2: per-proposal resolve + cls + dice; logits read hoisted ----------
__global__ __launch_bounds__(256) void final_kernel(
    const float* __restrict__ logits, const float* __restrict__ boxes,
    const int* __restrict__ gtcls, const float* __restrict__ gtbox,
    const float* __restrict__ costT, const unsigned int* __restrict__ matchcol,
    const float* __restrict__ proj, const float* __restrict__ gcrop,
    const float* __restrict__ gsum, float* __restrict__ part)
{
    int e = blockIdx.x;
    int b = e / N_PROP;
    int i = e - b * N_PROP;
    int tid = threadIdx.x;

    __shared__ int s_gi, s_any;
    __shared__ float s_l1, s_gl;
    __shared__ float4 s_red[4];

    // hoisted: box (all threads use it) + logit-with-label-0 focal (overlaps resolve)
    float4 a4 = ((const float4*)boxes)[e];
    float xlog = 0.f, f0 = 0.f;
    if (tid < N_CLS) {
        xlog = logits[(size_t)e * N_CLS + tid];
        f0 = focal_term(xlog, 0.f);
    }

    if (tid < 64) {
        int lane = tid;
        int ql = (lane < N_GT) ? lane : 0;
        float4 g4 = ((const float4*)gtbox)[b * N_GT + ql];

        float cx = (a4.x + a4.z) * 0.5f;
        float cy = (a4.y + a4.w) * 0.5f;
        int vb = 0;
        if (lane < N_GT) {
            int in_gt = (cx >= g4.x) & (cx <= g4.z) & (cy >= g4.y) & (cy <= g4.w);
            float gcx = (g4.x + g4.z) * 0.5f;
            float gcy = (g4.y + g4.w) * 0.5f;
            int in_ct = (fabsf(cx - gcx) <= CENTER_R) & (fabsf(cy - gcy) <= CENTER_R);
            vb = in_gt | in_ct;
        }
        int any = (__ballot(vb) != 0ULL);

        int gi = 0;
        float l1 = 0.f, gl = 0.f;
        if (any) {
            // resolve only for valid proposals (invalid: outputs independent of gi)
            float cv = 3e38f;
            int idx = 63;
            if (lane < N_GT) { cv = costT[(size_t)e * N_GT + lane]; idx = lane; }
            #pragma unroll
            for (int off = 1; off < 64; off <<= 1) {
                float oc = __shfl_xor(cv, off);
                int oi = __shfl_xor(idx, off);
                if (oc < cv || (oc == cv && oi < idx)) { cv = oc; idx = oi; }
            }
            int best = idx;

            int bit = 0;
            if (lane < N_GT)
                bit = (int)((matchcol[(b * N_GT + lane) * 10 + (i >> 5)] >> (i & 31)) & 1u);
            unsigned long long bm = __ballot(bit);
            int msk = (int)(bm & 0xFFFFFFULL);
            if (__popc(msk) > 1) msk = 1 << best;
            gi = msk ? (__ffs(msk) - 1) : best;

            float gx = __shfl(g4.x, gi), gy = __shfl(g4.y, gi);
            float gz = __shfl(g4.z, gi), gw = __shfl(g4.w, gi);
            float nb[4] = {a4.x / S_IMG, a4.y / S_IMG, a4.z / S_IMG, a4.w / S_IMG};
            float ng[4] = {gx / S_IMG, gy / S_IMG, gz / S_IMG, gw / S_IMG};
            l1 = (((fabsf(nb[0] - ng[0]) + fabsf(nb[1] - ng[1]))
                   + fabsf(nb[2] - ng[2])) + fabsf(nb[3] - ng[3]));
            gl = 1.f - giou_pair(nb, ng);
        }
        if (lane == 0) {
            s_gi = gi; s_any = any; s_l1 = l1; s_gl = gl;
        }
    }
    __syncthreads();

    int gi = s_gi;
    int any = s_any;
    float w = any ? 1.f : 0.f;

    // focal cls: f0 precomputed; only the matched-class lane recomputes (bit-exact)
    int mc = gtcls[b * N_GT + gi];
    float clsv = 0.f;
    if (tid < N_CLS)
        clsv = (any && tid == mc) ? focal_term(xlog, 1.f) : f0;

    // mask dice (direct proj/gcrop reads; maps L2-hot, ~12 blocks reuse each)
    float inter = 0.f, sp = 0.f;
    if (any) {
        const float* pimg = proj + (size_t)(b * N_GT + gi) * (HF * HF);
        const float* gcr = gcrop + (size_t)(b * N_GT + gi) * (TT * TT);
        const float fs = 64.0f / 896.0f;
        float px1 = a4.x * fs, py1 = a4.y * fs, px2 = a4.z * fs, py2 = a4.w * fs;
        #pragma unroll 4
        for (int t = tid; t < TT * TT; t += 256) {
            int ty = t / TT, tx = t - ty * TT;
            float qx = ((float)tx + 0.5f) / (float)TT;
            float qy = ((float)ty + 0.5f) / (float)TT;
            float X = px1 + (px2 - px1) * qx - 0.5f;
            float Y = py1 + (py2 - py1) * qy - 0.5f;
            float lg = bilin(pimg, HF, HF, X, Y);
            float mp = 1.f / (1.f + expf(-lg));
            inter += mp * gcr[t];
            sp += mp;
        }
    }

    #pragma unroll
    for (int off = 32; off > 0; off >>= 1) {
        clsv  += __shfl_xor(clsv, off);
        inter += __shfl_xor(inter, off);
        sp    += __shfl_xor(sp, off);
    }
    if ((tid & 63) == 0) s_red[tid >> 6] = make_float4(clsv, inter, sp, 0.f);
    __syncthreads();
    if (tid == 0) {
        float4 t = s_red[0];
        for (int k = 1; k < 4; k++) {
            t.x += s_red[k].x; t.y += s_red[k].y; t.z += s_red[k].z;
        }
        float sg = any ? gsum[b * N_GT + gi] : 0.f;
        float mterm = any ? (1.f - 2.f * t.y / (t.z + sg + EPSV)) * w : 0.f;
        float* pp = part + (size_t)e * 8;
        *(float4*)pp = make_float4(t.x, any ? s_l1 : 0.f, any ? s_gl : 0.f, mterm);
        pp[4] = w;
    }
}

// ---------- K3: reduce 1200x5 partials -> 4 outputs (single block) ----------
__global__ __launch_bounds__(256) void fin_kernel(
    const float* __restrict__ part, float* __restrict__ out)
{
    int tid = threadIdx.x;
    __shared__ float s_red[4][5];
    float s0 = 0.f, s1 = 0.f, s2 = 0.f, s3 = 0.f, s4 = 0.f;
    for (int p = tid; p < N_B * N_PROP; p += 256) {
        const float* pp = part + (size_t)p * 8;
        float4 v = *(const float4*)pp;
        s0 += v.x; s1 += v.y; s2 += v.z; s3 += v.w; s4 += pp[4];
    }
    #pragma unroll
    for (int off = 32; off > 0; off >>= 1) {
        s0 += __shfl_xor(s0, off);
        s1 += __shfl_xor(s1, off);
        s2 += __shfl_xor(s2, off);
        s3 += __shfl_xor(s3, off);
        s4 += __shfl_xor(s4, off);
    }
    if ((tid & 63) == 0) {
        int wv = tid >> 6;
        s_red[wv][0] = s0; s_red[wv][1] = s1; s_red[wv][2] = s2;
        s_red[wv][3] = s3; s_red[wv][4] = s4;
    }
    __syncthreads();
    if (tid == 0) {
        float t0 = 0.f, t1 = 0.f, t2 = 0.f, t3 = 0.f, t4 = 0.f;
        for (int k = 0; k < 4; k++) {
            t0 += s_red[k][0]; t1 += s_red[k][1]; t2 += s_red[k][2];
            t3 += s_red[k][3]; t4 += s_red[k][4];
        }
        out[0] = 2.0f * t0 / t4;
        out[1] = 5.0f * t1 / t4;
        out[2] = 2.0f * t2 / t4;
        out[3] = 5.0f * t3 / t4;
    }
}

// ---------- launch ----------

extern "C" void kernel_launch(void* const* d_in, const int* in_sizes, int n_in,
                              void* d_out, int out_size, void* d_ws, size_t ws_size,
                              hipStream_t stream)
{
    const float* logits = (const float*)d_in[0];
    const float* boxes  = (const float*)d_in[1];
    const float* feat   = (const float*)d_in[2];
    const float* wm     = (const float*)d_in[3];
    const int*   gtcls  = (const int*)d_in[4];
    const float* gtbox  = (const float*)d_in[5];
    const float* gmask  = (const float*)d_in[6];
    float* out = (float*)d_out;
    float* ws  = (float*)d_ws;

    float* costT = ws;                                        // 28800 floats
    unsigned int* matchcol = (unsigned int*)(ws + 28800);     // 960 u32
    float* part  = ws + 28800 + 960;                          // 9600 floats
    float* proj  = ws + 28800 + 960 + 9600;                   // 393216 floats
    float* gcrop = proj + 393216;                             // 75264 floats
    float* gsum  = gcrop + 75264;                             // 96 floats

    hipLaunchKernelGGL(prep_kernel, dim3(96 + 96 + 256), dim3(256), 0, stream,
                       feat, wm, logits, boxes, gtcls, gtbox, gmask,
                       proj, gcrop, gsum, costT, matchcol);
    hipLaunchKernelGGL(final_kernel, dim3(N_B * N_PROP), dim3(256), 0, stream,
                       logits, boxes, gtcls, gtbox, costT, matchcol, proj, gcrop,
                       gsum, part);
    hipLaunchKernelGGL(fin_kernel, dim3(1), dim3(256), 0, stream, part, out);
}